// Round 1
// baseline (2680.449 us; speedup 1.0000x reference)
//
#include <hip/hip_runtime.h>
#include <hip/hip_bf16.h>

typedef __bf16 bf16_t;
typedef bf16_t bf16x8 __attribute__((ext_vector_type(8)));
typedef float f32x4 __attribute__((ext_vector_type(4)));

// ---------------------------------------------------------------------------
// async global -> LDS, 16B per lane. LDS dest must be wave-uniform base;
// HW adds lane*16. Global src is per-lane.
// ---------------------------------------------------------------------------
__device__ __forceinline__ void load_lds16(const bf16_t* g, bf16_t* l) {
  __builtin_amdgcn_global_load_lds(
      (const __attribute__((address_space(1))) unsigned int*)g,
      (__attribute__((address_space(3))) unsigned int*)l,
      16, 0, 0);
}

// ---------------------------------------------------------------------------
// fp32 -> bf16 elementwise (vectorized x8)
// ---------------------------------------------------------------------------
__global__ void conv_f32_bf16(const float* __restrict__ src,
                              bf16_t* __restrict__ dst, long n) {
  long i = ((long)blockIdx.x * blockDim.x + threadIdx.x) * 8;
  if (i + 7 >= n) return;
  float4 a = *(const float4*)(src + i);
  float4 b = *(const float4*)(src + i + 4);
  bf16x8 v;
  v[0] = (bf16_t)a.x; v[1] = (bf16_t)a.y; v[2] = (bf16_t)a.z; v[3] = (bf16_t)a.w;
  v[4] = (bf16_t)b.x; v[5] = (bf16_t)b.y; v[6] = (bf16_t)b.z; v[7] = (bf16_t)b.w;
  *(bf16x8*)(dst + i) = v;
}

// bf16 -> fp32 (final h output)
__global__ void conv_bf16_f32(const bf16_t* __restrict__ src,
                              float* __restrict__ dst, long n) {
  long i = (long)blockIdx.x * blockDim.x + threadIdx.x;
  if (i >= n) return;
  dst[i] = (float)src[i];
}

// ---------------------------------------------------------------------------
// transpose + convert: src fp32 (K x N) row-major -> dst bf16 (N x K) row-major
// ---------------------------------------------------------------------------
__global__ void transpose_conv(const float* __restrict__ src,
                               bf16_t* __restrict__ dst, int Ksrc, int Nsrc) {
  __shared__ float tile[32][33];
  int n0 = blockIdx.x * 32, k0 = blockIdx.y * 32;
  int tx = threadIdx.x, ty = threadIdx.y;  // (32, 8)
#pragma unroll
  for (int i = 0; i < 32; i += 8)
    tile[ty + i][tx] = src[(long)(k0 + ty + i) * Nsrc + n0 + tx];
  __syncthreads();
#pragma unroll
  for (int i = 0; i < 32; i += 8)
    dst[(long)(n0 + ty + i) * Ksrc + k0 + tx] = (bf16_t)tile[tx][ty + i];
}

// ---------------------------------------------------------------------------
// m97-style GEMM: D[M,N] = A[M,K] @ Bt[N,K]^T + bias
// 128x128 tile, BK=32, 256 threads = 4 waves (2x2 of 64x64), single-buffer LDS,
// global_load_lds width-16 staging, mfma_f32_16x16x32_bf16.
// STORE_MODE 0: fp32 out.  1: bf16 out.
// Requires M%128==0, N%128==0, K%32==0.
// ---------------------------------------------------------------------------
template <int STORE_MODE>
__global__ __launch_bounds__(256) void gemm_bt_128(
    const bf16_t* __restrict__ A, const bf16_t* __restrict__ Bt,
    const float* __restrict__ bias, void* __restrict__ Dout,
    int M, int N, int K) {
  __shared__ bf16_t As[128 * 32];  // [row][k], k contiguous
  __shared__ bf16_t Bs[128 * 32];
  const int tid = threadIdx.x;
  const int lane = tid & 63;
  const int w = tid >> 6;
  const int wr = w >> 1, wc = w & 1;
  const int m0 = blockIdx.y * 128, n0 = blockIdx.x * 128;

  f32x4 acc[4][4] = {};

  const int r0 = tid >> 2;            // staging row 0..63
  const int kk = (tid & 3) * 8;       // staging k offset
  const int fr = lane & 15;           // fragment row/col
  const int fk = (lane >> 4) * 8;     // fragment k offset

  for (int k0 = 0; k0 < K; k0 += 32) {
    // stage A tile (128x32) and B tile (128x32), 2 chunks each
    load_lds16(A + (long)(m0 + r0) * K + k0 + kk, As + w * 512);
    load_lds16(A + (long)(m0 + 64 + r0) * K + k0 + kk, As + 2048 + w * 512);
    load_lds16(Bt + (long)(n0 + r0) * K + k0 + kk, Bs + w * 512);
    load_lds16(Bt + (long)(n0 + 64 + r0) * K + k0 + kk, Bs + 2048 + w * 512);
    asm volatile("s_waitcnt vmcnt(0)" ::: "memory");
    __syncthreads();

    bf16x8 af[4], bfx[4];
#pragma unroll
    for (int m = 0; m < 4; ++m)
      af[m] = *(const bf16x8*)&As[(wr * 64 + m * 16 + fr) * 32 + fk];
#pragma unroll
    for (int n = 0; n < 4; ++n)
      bfx[n] = *(const bf16x8*)&Bs[(wc * 64 + n * 16 + fr) * 32 + fk];
#pragma unroll
    for (int m = 0; m < 4; ++m)
#pragma unroll
      for (int n = 0; n < 4; ++n)
        acc[m][n] = __builtin_amdgcn_mfma_f32_16x16x32_bf16(af[m], bfx[n],
                                                            acc[m][n], 0, 0, 0);
    __syncthreads();
  }

  // epilogue: C/D layout col=lane&15, row=(lane>>4)*4+r
  const int fq = lane >> 4;
#pragma unroll
  for (int m = 0; m < 4; ++m) {
#pragma unroll
    for (int n = 0; n < 4; ++n) {
      int col = n0 + wc * 64 + n * 16 + fr;
      float bv = bias[col];
#pragma unroll
      for (int r = 0; r < 4; ++r) {
        int row = m0 + wr * 64 + m * 16 + fq * 4 + r;
        float v = acc[m][n][r] + bv;
        if (STORE_MODE == 0)
          ((float*)Dout)[(long)row * N + col] = v;
        else
          ((bf16_t*)Dout)[(long)row * N + col] = (bf16_t)v;
      }
    }
  }
}

// ---------------------------------------------------------------------------
// One recurrence step: h_t = relu(Z_t + h_{t-1} @ W_hh), in place over Z_t.
// M=128, N=2048, K=2048.  Tile 16x64 per WG, grid (32,8)=256 WGs.
// 4 waves per WG, each owns a K=512 slab, wave-private double-buffered LDS
// staging (no block barrier in K loop), LDS reduction epilogue.
// ---------------------------------------------------------------------------
__global__ __launch_bounds__(256) void rnn_step(
    const bf16_t* __restrict__ Hprev, bf16_t* __restrict__ Zio,
    const bf16_t* __restrict__ WhhT) {
  __shared__ bf16_t sA[4][2][512];    // per wave: 16 rows x 32 k
  __shared__ bf16_t sB[4][2][2048];   // per wave: 64 rows x 32 k
  __shared__ float sred[4][1024];     // per wave partial 16x64

  const int tid = threadIdx.x, lane = tid & 63, w = tid >> 6;
  const int m0 = blockIdx.y * 16, n0 = blockIdx.x * 64;
  const int H = 2048;
  const int kbase = w * 512;

  f32x4 acc[4] = {};

  const int arow = lane >> 2, akk = (lane & 3) * 8;
  const int fr = lane & 15, fk = (lane >> 4) * 8;

#define STAGE(buf, step)                                                      \
  {                                                                           \
    const int kb = kbase + (step) * 32;                                       \
    load_lds16(Hprev + (long)(m0 + arow) * H + kb + akk, &sA[w][buf][0]);     \
    _Pragma("unroll") for (int cc = 0; cc < 4; ++cc) {                        \
      int idx = cc * 64 + lane;                                               \
      load_lds16(WhhT + (long)(n0 + (idx >> 2)) * H + kb + (idx & 3) * 8,     \
                 &sB[w][buf][cc * 512]);                                      \
    }                                                                         \
  }

  STAGE(0, 0);
  int cur = 0;
  for (int step = 0; step < 16; ++step) {
    if (step < 15) {
      STAGE(cur ^ 1, step + 1);
      asm volatile("s_waitcnt vmcnt(5)" ::: "memory");
    } else {
      asm volatile("s_waitcnt vmcnt(0)" ::: "memory");
    }
    bf16x8 af = *(const bf16x8*)&sA[w][cur][fr * 32 + fk];
#pragma unroll
    for (int n = 0; n < 4; ++n) {
      bf16x8 bfr = *(const bf16x8*)&sB[w][cur][(n * 16 + fr) * 32 + fk];
      acc[n] = __builtin_amdgcn_mfma_f32_16x16x32_bf16(af, bfr, acc[n], 0, 0, 0);
    }
    cur ^= 1;
  }
#undef STAGE

  // write per-wave partials to LDS
  const int fq = lane >> 4;
#pragma unroll
  for (int n = 0; n < 4; ++n)
#pragma unroll
    for (int r = 0; r < 4; ++r)
      sred[w][(fq * 4 + r) * 64 + n * 16 + fr] = acc[n][r];
  __syncthreads();

  // reduce 4 waves, add Z, relu, store bf16 in place
#pragma unroll
  for (int e = 0; e < 4; ++e) {
    int j = tid + 256 * e;  // 0..1023
    int row = j >> 6, col = j & 63;
    float s = sred[0][j] + sred[1][j] + sred[2][j] + sred[3][j];
    long off = (long)(m0 + row) * H + n0 + col;
    float v = s + (float)Zio[off];
    Zio[off] = (bf16_t)(v > 0.f ? v : 0.f);
  }
}

// ---------------------------------------------------------------------------
extern "C" void kernel_launch(void* const* d_in, const int* in_sizes, int n_in,
                              void* d_out, int out_size, void* d_ws,
                              size_t ws_size, hipStream_t stream) {
  const float* x   = (const float*)d_in[0];  // (T,B,D)
  const float* h0  = (const float*)d_in[1];  // (B,H)
  const float* Wxh = (const float*)d_in[2];  // (D,H)
  const float* Whh = (const float*)d_in[3];  // (H,H)
  const float* bh  = (const float*)d_in[4];  // (H,)
  const float* Whq = (const float*)d_in[5];  // (H,Q)
  const float* bq  = (const float*)d_in[6];  // (Q,)
  float* out = (float*)d_out;

  const int T = 256, B = 128, D = 1024, H = 2048, Q = 1024;
  const long MB = (long)T * B;  // 32768

  char* ws = (char*)d_ws;
  bf16_t* x_bf = (bf16_t*)ws;  ws += MB * D * 2;          // 64 MiB
  bf16_t* Hbuf = (bf16_t*)ws;  ws += MB * H * 2;          // 128 MiB (Z, then h)
  bf16_t* h0bf = (bf16_t*)ws;  ws += (long)B * H * 2;
  bf16_t* WxhT = (bf16_t*)ws;  ws += (long)H * D * 2;
  bf16_t* WhhT = (bf16_t*)ws;  ws += (long)H * H * 2;
  bf16_t* WhqT = (bf16_t*)ws;  ws += (long)Q * H * 2;

  // --- convert inputs to bf16 (weights transposed to N x K) ---
  conv_f32_bf16<<<(int)(MB * D / 8 / 256), 256, 0, stream>>>(x, x_bf, MB * D);
  conv_f32_bf16<<<(int)((long)B * H / 8 / 256), 256, 0, stream>>>(h0, h0bf,
                                                                  (long)B * H);
  transpose_conv<<<dim3(H / 32, D / 32), dim3(32, 8), 0, stream>>>(Wxh, WxhT, D, H);
  transpose_conv<<<dim3(H / 32, H / 32), dim3(32, 8), 0, stream>>>(Whh, WhhT, H, H);
  transpose_conv<<<dim3(Q / 32, H / 32), dim3(32, 8), 0, stream>>>(Whq, WhqT, H, Q);

  // --- Z = x @ W_xh + b_h  (all timesteps), bf16 into Hbuf ---
  gemm_bt_128<1><<<dim3(H / 128, MB / 128), 256, 0, stream>>>(
      x_bf, WxhT, bh, Hbuf, (int)MB, H, D);

  // --- sequential recurrence: Hbuf[t] <- relu(Z_t + h_{t-1} @ W_hh) ---
  for (int t = 0; t < T; ++t) {
    const bf16_t* hprev = (t == 0) ? h0bf : Hbuf + (long)(t - 1) * B * H;
    rnn_step<<<dim3(H / 64, B / 16), 256, 0, stream>>>(
        hprev, Hbuf + (long)t * B * H, WhhT);
  }

  // --- out = H @ W_hq + b_q  (fp32 straight to d_out) ---
  gemm_bt_128<0><<<dim3(Q / 128, MB / 128), 256, 0, stream>>>(
      Hbuf, WhqT, bq, out, (int)MB, Q, H);

  // --- final h (fp32) appended after (T*B, Q) block ---
  conv_bf16_f32<<<(int)((long)B * H / 256), 256, 0, stream>>>(
      Hbuf + (long)(T - 1) * B * H, out + MB * Q, (long)B * H);
}